// Round 3
// baseline (1695.904 us; speedup 1.0000x reference)
//
#include <hip/hip_runtime.h>
#include <math.h>

#define NT 8192
#define DIM 7168
#define NE 256

// ---------------- GEMM: scores = sigmoid(x @ W^T), full fp64 ----------------
// BM=BN=64, BK=16, 256 threads, 4x4 micro-tile. CDNA4 has no fp32 MFMA; we need
// np-reference-grade numerics for exact top-k, so accumulate in fp64 (v_fma_f64,
// half fp32 VALU rate -> ~380us floor). LDS staged as fp64 (convert once/element).
#define BM 64
#define BN 64
#define BK 16
#define PADD 65   // doubles per row: staging writes spread 2 lanes/bank (free)

__global__ __launch_bounds__(256) void gate_gemm_f64(const float* __restrict__ x,
                                                     const float* __restrict__ w,
                                                     double* __restrict__ scores) {
    __shared__ double As[BK][PADD];   // [k][m]
    __shared__ double Bs[BK][PADD];   // [k][e]
    const int eb = blockIdx.x;          // 0..3
    const int mb = blockIdx.y;          // 0..127
    const int t  = (int)threadIdx.x;
    const int lrow = t >> 2;            // 0..63 : tile row this thread stages
    const int kq   = (t & 3) << 2;      // 0,4,8,12 : k offset (float4)
    const int ty = t >> 4;              // 0..15 : m micro-group
    const int tx = t & 15;              // 0..15 : n micro-group

    const float* ag = x + (size_t)(mb * BM + lrow) * DIM + kq;
    const float* bg = w + (size_t)(eb * BN + lrow) * DIM + kq;

    double acc[4][4];
    #pragma unroll
    for (int i = 0; i < 4; ++i)
        #pragma unroll
        for (int j = 0; j < 4; ++j) acc[i][j] = 0.0;

    for (int kb = 0; kb < DIM; kb += BK) {
        const float4 av = *(const float4*)(ag + kb);
        const float4 bv = *(const float4*)(bg + kb);
        __syncthreads();
        As[kq + 0][lrow] = (double)av.x; As[kq + 1][lrow] = (double)av.y;
        As[kq + 2][lrow] = (double)av.z; As[kq + 3][lrow] = (double)av.w;
        Bs[kq + 0][lrow] = (double)bv.x; Bs[kq + 1][lrow] = (double)bv.y;
        Bs[kq + 2][lrow] = (double)bv.z; Bs[kq + 3][lrow] = (double)bv.w;
        __syncthreads();
        #pragma unroll
        for (int kk = 0; kk < BK; ++kk) {
            double ar[4], br[4];
            #pragma unroll
            for (int i = 0; i < 4; ++i) ar[i] = As[kk][ty * 4 + i];
            #pragma unroll
            for (int j = 0; j < 4; ++j) br[j] = Bs[kk][tx * 4 + j];
            #pragma unroll
            for (int i = 0; i < 4; ++i)
                #pragma unroll
                for (int j = 0; j < 4; ++j)
                    acc[i][j] = fma(ar[i], br[j], acc[i][j]);
        }
    }
    #pragma unroll
    for (int i = 0; i < 4; ++i) {
        const int m = mb * BM + ty * 4 + i;
        double4 o;
        o.x = 1.0 / (1.0 + exp(-acc[i][0]));
        o.y = 1.0 / (1.0 + exp(-acc[i][1]));
        o.z = 1.0 / (1.0 + exp(-acc[i][2]));
        o.w = 1.0 / (1.0 + exp(-acc[i][3]));
        *(double4*)&scores[(size_t)m * NE + eb * BN + tx * 4] = o;
    }
}

// ---------------- Routing: one wave (64 lanes) per token, fp64 ----------------
// lane l owns experts 4l..4l+3. Group g = experts 32g..32g+31 = lanes 8g..8g+7.
__global__ __launch_bounds__(256) void gate_route_f64(const double* __restrict__ scores,
                                                      const float* __restrict__ bias,
                                                      float* __restrict__ out) {
    const int t = (int)threadIdx.x;
    const int lane = t & 63;
    const int token = blockIdx.x * 4 + (t >> 6);

    const double4 sc4 = *(const double4*)&scores[(size_t)token * NE + lane * 4];
    const float4 bi4 = *(const float4*)&bias[lane * 4];
    const double orig[4] = {sc4.x, sc4.y, sc4.z, sc4.w};
    const double sb[4] = {orig[0] + (double)bi4.x, orig[1] + (double)bi4.y,
                          orig[2] + (double)bi4.z, orig[3] + (double)bi4.w};

    // per-lane top-2 of 4 (values only)
    const double m1 = fmax(sb[0], sb[1]), m2 = fmin(sb[0], sb[1]);
    const double m3 = fmax(sb[2], sb[3]), m4 = fmin(sb[2], sb[3]);
    double hi = fmax(m1, m3);
    double lo = fmax(fmin(m1, m3), fmax(m2, m4));
    // merge top-2 pairs across the 8 lanes of the group
    #pragma unroll
    for (int off = 1; off < 8; off <<= 1) {
        const double oh = __shfl_xor(hi, off);
        const double ol = __shfl_xor(lo, off);
        const double nhi = fmax(hi, oh);
        const double nlo = fmax(fmin(hi, oh), fmax(lo, ol));
        hi = nhi; lo = nlo;
    }
    const double gsum = hi + lo;         // group score (top1 + top2, ref fp order)
    const int g = lane >> 3;

    // rank of my group among 8 (value desc, lower index wins ties) -> top-4 selected
    int rank = 0;
    #pragma unroll
    for (int j = 0; j < 8; ++j) {
        const double gj = __shfl(gsum, j * 8);
        rank += (gj > gsum) || (gj == gsum && j < g);
    }
    const bool sel = rank < 4;

    // masked scores: unselected groups are EXACTLY 0.0 (matches reference sg*mask)
    double mv[4];
    #pragma unroll
    for (int i = 0; i < 4; ++i) mv[i] = sel ? sb[i] : 0.0;

    double wsel[8];
    int isel[8];
    double wsum = 0.0;
    #pragma unroll
    for (int r = 0; r < 8; ++r) {
        // local argmax of 4 (strict > : lower index wins ties)
        double v = mv[0]; int ii = 0;
        if (mv[1] > v) { v = mv[1]; ii = 1; }
        if (mv[2] > v) { v = mv[2]; ii = 2; }
        if (mv[3] > v) { v = mv[3]; ii = 3; }
        int idx = lane * 4 + ii;
        // wave argmax butterfly (value desc, lower index on ties)
        #pragma unroll
        for (int off = 1; off < 64; off <<= 1) {
            const double ov = __shfl_xor(v, off);
            const int    oi = __shfl_xor(idx, off);
            if (ov > v || (ov == v && oi < idx)) { v = ov; idx = oi; }
        }
        const int owner = idx >> 2, slot = idx & 3;   // uniform across lanes
        const double os = (slot == 0) ? orig[0] : (slot == 1) ? orig[1]
                        : (slot == 2) ? orig[2] : orig[3];
        const double ow = __shfl(os, owner);          // ORIGINAL (un-biased) score
        wsel[r] = ow; isel[r] = idx; wsum += ow;
        if (lane == owner) {                          // remove from candidate set
            if      (slot == 0) mv[0] = -INFINITY;
            else if (slot == 1) mv[1] = -INFINITY;
            else if (slot == 2) mv[2] = -INFINITY;
            else                mv[3] = -INFINITY;
        }
    }

    if (lane == 0) {
        const double scale = 2.5 / wsum;
        #pragma unroll
        for (int r = 0; r < 8; ++r) {
            out[(size_t)token * 8 + r] = (float)(wsel[r] * scale);          // weights
            out[(size_t)NT * 8 + (size_t)token * 8 + r] = (float)isel[r];  // idx as f32
        }
    }
}

extern "C" void kernel_launch(void* const* d_in, const int* in_sizes, int n_in,
                              void* d_out, int out_size, void* d_ws, size_t ws_size,
                              hipStream_t stream) {
    const float* x    = (const float*)d_in[0];
    // d_in[1] = token_mask (all ones; unused by the reference math)
    const float* w    = (const float*)d_in[2];
    const float* bias = (const float*)d_in[3];
    float* out     = (float*)d_out;
    double* scores = (double*)d_ws;   // 8192*256 fp64 = 16.8 MB scratch

    dim3 gGemm(NE / BN, NT / BM);   // (4, 128) = 512 blocks
    gate_gemm_f64<<<gGemm, 256, 0, stream>>>(x, w, scores);
    gate_route_f64<<<NT / 4, 256, 0, stream>>>(scores, bias, out);
}

// Round 5
// 1284.926 us; speedup vs baseline: 1.3198x; 1.3198x over previous
//
#include <hip/hip_runtime.h>
#include <math.h>

#define NT 8192
#define DIM 7168
#define NE 256

// ---------------- GEMM: scores = sigmoid(x @ W^T), full fp64 ----------------
// fp64 accumulation (np ref is fp64-grade; R3 absmax was exactly 0.0).
// R4 fixes vs R3: (1) strided micro-tile (m=i*16+ty, e=j*16+tx) -> fragment
// reads are ds_read_b64 at 128B stride: 16 addrs x 2 banks = all 32 banks,
// broadcast x4 -> conflict-free (R3 had 4.1e8 conflicts from merged b128);
// (2) register prefetch of tile kb+1 before computing kb (hides ~900cy HBM
// latency under ~1024cy of fp64 FMA). Same k-order => bitwise-identical scores.
#define BM 64
#define BN 64
#define BK 16

__global__ __launch_bounds__(256) void gate_gemm_f64(const float* __restrict__ x,
                                                     const float* __restrict__ w,
                                                     double* __restrict__ scores) {
    __shared__ double As[BK][BM];   // [k][m], no pad (reads are stride-16-dbl)
    __shared__ double Bs[BK][BN];   // [k][e]
    const int eb = blockIdx.x;          // 0..3
    const int mb = blockIdx.y;          // 0..127
    const int t  = (int)threadIdx.x;
    const int lrow = t >> 2;            // 0..63 : tile row this thread stages
    const int kq   = (t & 3) << 2;      // 0,4,8,12 : k offset (float4)
    const int ty = t >> 4;              // 0..15 : m fragment lane
    const int tx = t & 15;              // 0..15 : e fragment lane

    const float* ag = x + (size_t)(mb * BM + lrow) * DIM + kq;
    const float* bg = w + (size_t)(eb * BN + lrow) * DIM + kq;

    double acc[4][4];
    #pragma unroll
    for (int i = 0; i < 4; ++i)
        #pragma unroll
        for (int j = 0; j < 4; ++j) acc[i][j] = 0.0;

    float4 av = *(const float4*)ag;     // prefetch tile 0
    float4 bv = *(const float4*)bg;

    for (int kb = 0; kb < DIM; kb += BK) {
        __syncthreads();
        As[kq + 0][lrow] = (double)av.x; As[kq + 1][lrow] = (double)av.y;
        As[kq + 2][lrow] = (double)av.z; As[kq + 3][lrow] = (double)av.w;
        Bs[kq + 0][lrow] = (double)bv.x; Bs[kq + 1][lrow] = (double)bv.y;
        Bs[kq + 2][lrow] = (double)bv.z; Bs[kq + 3][lrow] = (double)bv.w;
        __syncthreads();
        if (kb + BK < DIM) {            // prefetch next tile (uniform branch)
            av = *(const float4*)(ag + kb + BK);
            bv = *(const float4*)(bg + kb + BK);
        }
        #pragma unroll
        for (int kk = 0; kk < BK; ++kk) {
            double ar[4], br[4];
            #pragma unroll
            for (int i = 0; i < 4; ++i) ar[i] = As[kk][i * 16 + ty];
            #pragma unroll
            for (int j = 0; j < 4; ++j) br[j] = Bs[kk][j * 16 + tx];
            #pragma unroll
            for (int i = 0; i < 4; ++i)
                #pragma unroll
                for (int j = 0; j < 4; ++j)
                    acc[i][j] = fma(ar[i], br[j], acc[i][j]);
        }
    }
    #pragma unroll
    for (int i = 0; i < 4; ++i) {
        const int m = mb * BM + i * 16 + ty;
        #pragma unroll
        for (int j = 0; j < 4; ++j) {
            const double s = 1.0 / (1.0 + exp(-acc[i][j]));
            scores[(size_t)m * NE + eb * BN + j * 16 + tx] = s;
        }
    }
}

// ---------------- Routing: one wave (64 lanes) per token, fp64 ----------------
// lane l owns experts 4l..4l+3. Group g = experts 32g..32g+31 = lanes 8g..8g+7.
__global__ __launch_bounds__(256) void gate_route_f64(const double* __restrict__ scores,
                                                      const float* __restrict__ bias,
                                                      float* __restrict__ out) {
    const int t = (int)threadIdx.x;
    const int lane = t & 63;
    const int token = blockIdx.x * 4 + (t >> 6);

    const double4 sc4 = *(const double4*)&scores[(size_t)token * NE + lane * 4];
    const float4 bi4 = *(const float4*)&bias[lane * 4];
    const double orig[4] = {sc4.x, sc4.y, sc4.z, sc4.w};
    const double sb[4] = {orig[0] + (double)bi4.x, orig[1] + (double)bi4.y,
                          orig[2] + (double)bi4.z, orig[3] + (double)bi4.w};

    // per-lane top-2 of 4 (values only)
    const double m1 = fmax(sb[0], sb[1]), m2 = fmin(sb[0], sb[1]);
    const double m3 = fmax(sb[2], sb[3]), m4 = fmin(sb[2], sb[3]);
    double hi = fmax(m1, m3);
    double lo = fmax(fmin(m1, m3), fmax(m2, m4));
    // merge top-2 pairs across the 8 lanes of the group
    #pragma unroll
    for (int off = 1; off < 8; off <<= 1) {
        const double oh = __shfl_xor(hi, off);
        const double ol = __shfl_xor(lo, off);
        const double nhi = fmax(hi, oh);
        const double nlo = fmax(fmin(hi, oh), fmax(lo, ol));
        hi = nhi; lo = nlo;
    }
    const double gsum = hi + lo;         // group score (top1 + top2, ref fp order)
    const int g = lane >> 3;

    // rank of my group among 8 (value desc, lower index wins ties) -> top-4 selected
    int rank = 0;
    #pragma unroll
    for (int j = 0; j < 8; ++j) {
        const double gj = __shfl(gsum, j * 8);
        rank += (gj > gsum) || (gj == gsum && j < g);
    }
    const bool sel = rank < 4;

    // masked scores: unselected groups are EXACTLY 0.0 (matches reference sg*mask)
    double mv[4];
    #pragma unroll
    for (int i = 0; i < 4; ++i) mv[i] = sel ? sb[i] : 0.0;

    double wsel[8];
    int isel[8];
    double wsum = 0.0;
    #pragma unroll
    for (int r = 0; r < 8; ++r) {
        // local argmax of 4 (strict > : lower index wins ties)
        double v = mv[0]; int ii = 0;
        if (mv[1] > v) { v = mv[1]; ii = 1; }
        if (mv[2] > v) { v = mv[2]; ii = 2; }
        if (mv[3] > v) { v = mv[3]; ii = 3; }
        int idx = lane * 4 + ii;
        // wave argmax butterfly (value desc, lower index on ties)
        #pragma unroll
        for (int off = 1; off < 64; off <<= 1) {
            const double ov = __shfl_xor(v, off);
            const int    oi = __shfl_xor(idx, off);
            if (ov > v || (ov == v && oi < idx)) { v = ov; idx = oi; }
        }
        const int owner = idx >> 2, slot = idx & 3;   // uniform across lanes
        const double os = (slot == 0) ? orig[0] : (slot == 1) ? orig[1]
                        : (slot == 2) ? orig[2] : orig[3];
        const double ow = __shfl(os, owner);          // ORIGINAL (un-biased) score
        wsel[r] = ow; isel[r] = idx; wsum += ow;
        if (lane == owner) {                          // remove from candidate set
            if      (slot == 0) mv[0] = -INFINITY;
            else if (slot == 1) mv[1] = -INFINITY;
            else if (slot == 2) mv[2] = -INFINITY;
            else                mv[3] = -INFINITY;
        }
    }

    if (lane == 0) {
        const double scale = 2.5 / wsum;
        #pragma unroll
        for (int r = 0; r < 8; ++r) {
            out[(size_t)token * 8 + r] = (float)(wsel[r] * scale);          // weights
            out[(size_t)NT * 8 + (size_t)token * 8 + r] = (float)isel[r];  // idx as f32
        }
    }
}

extern "C" void kernel_launch(void* const* d_in, const int* in_sizes, int n_in,
                              void* d_out, int out_size, void* d_ws, size_t ws_size,
                              hipStream_t stream) {
    const float* x    = (const float*)d_in[0];
    // d_in[1] = token_mask (all ones; unused by the reference math)
    const float* w    = (const float*)d_in[2];
    const float* bias = (const float*)d_in[3];
    float* out     = (float*)d_out;
    double* scores = (double*)d_ws;   // 8192*256 fp64 = 16.8 MB scratch

    dim3 gGemm(NE / BN, NT / BM);   // (4, 128) = 512 blocks
    gate_gemm_f64<<<gGemm, 256, 0, stream>>>(x, w, scores);
    gate_route_f64<<<NT / 4, 256, 0, stream>>>(scores, bias, out);
}